// Round 7
// baseline (664.643 us; speedup 1.0000x reference)
//
#include <hip/hip_runtime.h>
#include <cstddef>

#define B_    4
#define CIN_  256
#define COUT_ 256
#define H_    64
#define W_    64
#define KK_   9
#define G_    4
#define PAD_  1
#define TPX   64          // pixels per block = one full W row
#define NSL   9           // steps per block: 1 group * 9 taps, K=64 each

// ws layout (bytes)
#define WS_XT   0u          // 8 MB bf16 NHWC x
#define WS_WB   8388608u    // 1.18 MB bf16 weights
#define WS_P23  9568256u    // 16.8 MB: uint per out elem = [p2|p3] bf16 pair
#define WS_CNT  26345472u   // 256 x int counters

typedef short bf16x8 __attribute__((ext_vector_type(8)));
typedef float f32x4  __attribute__((ext_vector_type(4)));
typedef __attribute__((address_space(1))) const unsigned int* gptr_t;
typedef __attribute__((address_space(3))) unsigned int*       lptr_t;

__device__ __forceinline__ unsigned short f2bf(float v) {
    unsigned int u = __float_as_uint(v);
    u += 0x7fffu + ((u >> 16) & 1u);
    return (unsigned short)(u >> 16);
}
__device__ __forceinline__ float f_lo(unsigned int u) { return __uint_as_float(u << 16); }
__device__ __forceinline__ float f_hi(unsigned int u) { return __uint_as_float(u & 0xffff0000u); }

// Fused prep: blocks [0,512) transpose x -> NHWC bf16; blocks [512,1088) build wb.
__global__ __launch_bounds__(256) void prep_kernel(const float* __restrict__ x,
                                                   const float* __restrict__ w,
                                                   unsigned short* __restrict__ xT,
                                                   unsigned short* __restrict__ wb) {
    const int tid = threadIdx.x;
    if (blockIdx.x < 512) {
        __shared__ unsigned short s[128][66];
        const int bh    = blockIdx.x >> 1;
        const int chalf = blockIdx.x & 1;
        const size_t src_base = ((size_t)(bh >> 6) * CIN_ + chalf * 128) * (H_ * W_) + (bh & 63) * W_;
        #pragma unroll 4
        for (int k = 0; k < 32; ++k) {
            int i = k * 256 + tid;
            int c = i >> 6, wq = i & 63;
            s[c][wq] = f2bf(x[src_base + (size_t)c * (H_ * W_) + wq]);
        }
        __syncthreads();
        #pragma unroll 4
        for (int k = 0; k < 16; ++k) {
            int j  = k * 256 + tid;
            int c2 = (j & 63) * 2, wq = j >> 6;
            unsigned int lo = s[c2][wq], hi = s[c2 + 1][wq];
            *(unsigned int*)(xT + ((size_t)bh * 64 + wq) * 256 + chalf * 128 + c2) = lo | (hi << 16);
        }
    } else {
        // wb: 36 tiles [g][kk] of [o][pos*8+e], pos = j ^ (o&7), c = g*64 + j*8 + e
        const int base = (blockIdx.x - 512) * 1024 + tid * 4;
        #pragma unroll
        for (int u = 0; u < 4; ++u) {
            int idx = base + u;
            int e   = idx & 7;
            int pos = (idx >> 3) & 7;
            int o   = (idx >> 6) & 255;
            int t   = idx >> 14;
            int g   = t / 9, kk = t - g * 9;
            int j   = pos ^ (o & 7);
            int c   = g * 64 + j * 8 + e;
            wb[idx] = f2bf(w[(o * CIN_ + c) * KK_ + kk]);
        }
    }
}

// Main: block = (b, h row, deform group kq). Partial GEMM over K=576 quarter.
// kq0/kq1 -> bf16 pair packed in out words; kq2/kq3 -> ws. Last block per row reduces.
__global__ __launch_bounds__(512, 8) void dcn_kernel(
    const unsigned short* __restrict__ xT, const float* __restrict__ y,
    const float* __restrict__ w_off, const unsigned short* __restrict__ wb,
    unsigned int* __restrict__ outu,        // d_out viewed as uint (bf16 pair)
    unsigned int* __restrict__ p23,         // ws partial pair for kq2/kq3
    int* __restrict__ cnt)
{
    __shared__ unsigned short s_W[COUT_ * 64];   // 32 KB
    __shared__ unsigned short s_S[TPX * 64];     //  8 KB  (reused as flag after loop)

    const int tid = threadIdx.x;
    const int bid = blockIdx.x;                  // 1024 blocks = 4/CU
    // XCD swizzle: bid&7 fixes (kq, b-low): wb quarter (288 KB) + x slab stay in L2
    const int kq  = bid & 3;
    const int bl  = (bid >> 2) & 1;
    const int loc = bid >> 3;                    // [0,128)
    const int h   = loc & 63;
    const int b   = (loc >> 6) * 2 + bl;
    const int row = b * 64 + h;

    // sampling mapping: thread -> (pixel sp, 8-ch chunk c8); 64*8 = 512 items
    const int sp = tid & 63;
    const int c8 = tid >> 6;

    const float yv0 = y[((b * 2 + 0) * H_ + h) * W_ + sp];
    const float yv1 = y[((b * 2 + 1) * H_ + h) * W_ + sp];

    // mfma mapping: 8 waves, wave = 64 outs (oh) x 32 px (pg)
    const int lane = tid & 63, wave = tid >> 6;
    const int pg  = wave & 1, oh = wave >> 1;
    const int l15 = lane & 15, kq4 = lane >> 4, sw = l15 & 7;

    f32x4 acc[8];
    #pragma unroll
    for (int i = 0; i < 8; ++i) acc[i] = (f32x4){0.f, 0.f, 0.f, 0.f};

    const size_t xbase = (size_t)b * (H_ * W_ * 256) + c8 * 8;

    for (int sl = 0; sl < NSL; ++sl) {
        const int s  = kq * NSL + sl;           // global step 0..35
        const int kk = sl;

        __syncthreads();   // all waves done reading s_W/s_S from prev step

        // ---- DMA W tile: 32 KB async global->LDS ----
        {
            const unsigned short* src = wb + (size_t)s * 16384;
            #pragma unroll
            for (int j = 0; j < 4; ++j) {
                const int off = (j * 512 + tid) * 8;
                __builtin_amdgcn_global_load_lds((gptr_t)(src + off),
                                                 (lptr_t)(s_W + off), 16, 0, 0);
            }
        }

        // ---- sample: 64 px x 64 ch ----
        {
            const float4 co = *(const float4*)(w_off + s * 4);
            const float dy = fmaf(yv0, co.x, yv1 * co.y);
            const float dx = fmaf(yv0, co.z, yv1 * co.w);
            const float yc = (float)(h + (kk / 3) - PAD_) + dy;
            const float xc = (float)(sp + (kk % 3) - PAD_) + dx;
            const float yf = floorf(yc), xf = floorf(xc);
            const float wy = yc - yf,    wx = xc - xf;
            const int   yi = (int)yf,    xi = (int)xf;
            float w00 = (1.f - wy) * (1.f - wx);
            float w01 = (1.f - wy) * wx;
            float w10 = wy * (1.f - wx);
            float w11 = wy * wx;
            const bool y0ok = (yi >= 0) & (yi < H_);
            const bool y1ok = (yi >= -1) & (yi < H_ - 1);
            const bool x0ok = (xi >= 0) & (xi < W_);
            const bool x1ok = (xi >= -1) & (xi < W_ - 1);
            w00 = (y0ok & x0ok) ? w00 : 0.f;
            w01 = (y0ok & x1ok) ? w01 : 0.f;
            w10 = (y1ok & x0ok) ? w10 : 0.f;
            w11 = (y1ok & x1ok) ? w11 : 0.f;
            const int y0c = min(max(yi, 0), H_ - 1);
            const int y1c = min(max(yi + 1, 0), H_ - 1);
            const int x0c = min(max(xi, 0), W_ - 1);
            const int x1c = min(max(xi + 1, 0), W_ - 1);
            const unsigned short* xb = xT + xbase + kq * 64;
            const uint4 A  = *(const uint4*)(xb + ((size_t)y0c * W_ + x0c) * 256);
            const uint4 Bv = *(const uint4*)(xb + ((size_t)y0c * W_ + x1c) * 256);
            const uint4 C  = *(const uint4*)(xb + ((size_t)y1c * W_ + x0c) * 256);
            const uint4 D  = *(const uint4*)(xb + ((size_t)y1c * W_ + x1c) * 256);
            const unsigned int av[4] = {A.x, A.y, A.z, A.w};
            const unsigned int bv[4] = {Bv.x, Bv.y, Bv.z, Bv.w};
            const unsigned int cv[4] = {C.x, C.y, C.z, C.w};
            const unsigned int dv[4] = {D.x, D.y, D.z, D.w};
            unsigned int res[4];
            #pragma unroll
            for (int q = 0; q < 4; ++q) {
                float rl = w00 * f_lo(av[q]);
                rl = fmaf(w01, f_lo(bv[q]), rl);
                rl = fmaf(w10, f_lo(cv[q]), rl);
                rl = fmaf(w11, f_lo(dv[q]), rl);
                float rh = w00 * f_hi(av[q]);
                rh = fmaf(w01, f_hi(bv[q]), rh);
                rh = fmaf(w10, f_hi(cv[q]), rh);
                rh = fmaf(w11, f_hi(dv[q]), rh);
                res[q] = __builtin_amdgcn_perm(__float_as_uint(rh),
                                               __float_as_uint(rl), 0x07060302u);
            }
            *(uint4*)(s_S + sp * 64 + ((c8 ^ (sp & 7)) * 8)) =
                make_uint4(res[0], res[1], res[2], res[3]);
        }

        __syncthreads();   // drains DMA + LDS stores

        // ---- MFMA: wave = [oh*64,+64) outs x [pg*32,+32) px, K=64 ----
        bf16x8 bf[2][2], af[2][4];
        #pragma unroll
        for (int kh = 0; kh < 2; ++kh) {
            const int pos = ((kh * 4 + kq4) ^ sw) * 8;
            #pragma unroll
            for (int nt = 0; nt < 2; ++nt)
                bf[kh][nt] = *(const bf16x8*)(s_S + (pg * 32 + nt * 16 + l15) * 64 + pos);
            #pragma unroll
            for (int mt = 0; mt < 4; ++mt)
                af[kh][mt] = *(const bf16x8*)(s_W + (oh * 64 + mt * 16 + l15) * 64 + pos);
        }
        #pragma unroll
        for (int kh = 0; kh < 2; ++kh)
            #pragma unroll
            for (int nt = 0; nt < 2; ++nt)
                #pragma unroll
                for (int mt = 0; mt < 4; ++mt)
                    acc[nt * 4 + mt] = __builtin_amdgcn_mfma_f32_16x16x32_bf16(
                        af[kh][mt], bf[kh][nt], acc[nt * 4 + mt], 0, 0, 0);
    }

    // ---- store bf16 partial into packed pair word (lo: kq even, hi: kq odd) ----
    {
        unsigned short* pdst =
            (unsigned short*)((kq < 2) ? outu : p23) + (kq & 1);
        #pragma unroll
        for (int nt = 0; nt < 2; ++nt) {
            const int px = pg * 32 + nt * 16 + l15;
            #pragma unroll
            for (int mt = 0; mt < 4; ++mt) {
                const int obase = oh * 64 + mt * 16 + kq4 * 4;
                #pragma unroll
                for (int r = 0; r < 4; ++r) {
                    const size_t gi = (((size_t)b * COUT_ + obase + r) * H_ + h) * W_ + px;
                    pdst[gi * 2] = f2bf(acc[nt * 4 + mt][r]);
                }
            }
        }
    }

    // ---- last-block-per-row reduction: out = relu(p0+p1+p2+p3) ----
    __threadfence();
    __syncthreads();
    int* s_flag = (int*)s_S;           // s_S dead after MFMA loop
    if (tid == 0) s_flag[0] = (atomicAdd(&cnt[row], 1) == 3);
    __syncthreads();
    if (s_flag[0]) {
        __threadfence();               // acquire: see other blocks' partials
        const size_t base = (size_t)b * (COUT_ * H_ * W_) + (size_t)h * W_;
        float* outf = (float*)outu;
        #pragma unroll
        for (int j = 0; j < 8; ++j) {
            const int e = j * 2048 + tid * 4;     // o*64 + w within the row
            const int o = e >> 6, wq = e & 63;
            const size_t gi = base + (size_t)o * (H_ * W_) + wq;
            const uint4 a = *(const uint4*)(outu + gi);
            const uint4 c = *(const uint4*)(p23 + gi);
            float4 r;
            r.x = fmaxf(f_lo(a.x) + f_hi(a.x) + f_lo(c.x) + f_hi(c.x), 0.f);
            r.y = fmaxf(f_lo(a.y) + f_hi(a.y) + f_lo(c.y) + f_hi(c.y), 0.f);
            r.z = fmaxf(f_lo(a.z) + f_hi(a.z) + f_lo(c.z) + f_hi(c.z), 0.f);
            r.w = fmaxf(f_lo(a.w) + f_hi(a.w) + f_lo(c.w) + f_hi(c.w), 0.f);
            *(float4*)(outf + gi) = r;
        }
    }
}

extern "C" void kernel_launch(void* const* d_in, const int* in_sizes, int n_in,
                              void* d_out, int out_size, void* d_ws, size_t ws_size,
                              hipStream_t stream) {
    const float* x     = (const float*)d_in[0];
    const float* y     = (const float*)d_in[1];
    const float* w_off = (const float*)d_in[2];
    const float* w_def = (const float*)d_in[3];

    unsigned short* xT  = (unsigned short*)((char*)d_ws + WS_XT);
    unsigned short* wb  = (unsigned short*)((char*)d_ws + WS_WB);
    unsigned int*   p23 = (unsigned int*)((char*)d_ws + WS_P23);
    int*            cnt = (int*)((char*)d_ws + WS_CNT);

    hipMemsetAsync(cnt, 0, 256 * sizeof(int), stream);
    prep_kernel<<<1088, 256, 0, stream>>>(x, w_def, xT, wb);
    dcn_kernel<<<1024, 512, 0, stream>>>(xT, y, w_off, wb,
                                         (unsigned int*)d_out, p23, cnt);
}

// Round 8
// 616.882 us; speedup vs baseline: 1.0774x; 1.0774x over previous
//
#include <hip/hip_runtime.h>
#include <cstddef>

#define B_    4
#define CIN_  256
#define COUT_ 256
#define H_    64
#define W_    64
#define KK_   9
#define G_    4
#define PAD_  1
#define TPX   64          // pixels per block = one full W row
#define NSL   9           // steps per block: 1 group * 9 taps, K=64 each

// ws layout (bytes)
#define WS_XT   0u          // 8 MB bf16 NHWC x
#define WS_WB   8388608u    // 1.18 MB bf16 weights
#define WS_P23  9568256u    // 16.8 MB: uint per out elem = [p2|p3] bf16 pair
#define WS_CNT  26345472u   // 256 x int counters

typedef short bf16x8 __attribute__((ext_vector_type(8)));
typedef float f32x4  __attribute__((ext_vector_type(4)));
typedef __attribute__((address_space(1))) const unsigned int* gptr_t;
typedef __attribute__((address_space(3))) unsigned int*       lptr_t;

__device__ __forceinline__ unsigned short f2bf(float v) {
    unsigned int u = __float_as_uint(v);
    u += 0x7fffu + ((u >> 16) & 1u);
    return (unsigned short)(u >> 16);
}
__device__ __forceinline__ float f_lo(unsigned int u) { return __uint_as_float(u << 16); }
__device__ __forceinline__ float f_hi(unsigned int u) { return __uint_as_float(u & 0xffff0000u); }

// Fused prep: blocks [0,512) transpose x -> NHWC bf16; blocks [512,1088) build wb.
__global__ __launch_bounds__(256) void prep_kernel(const float* __restrict__ x,
                                                   const float* __restrict__ w,
                                                   unsigned short* __restrict__ xT,
                                                   unsigned short* __restrict__ wb) {
    const int tid = threadIdx.x;
    if (blockIdx.x < 512) {
        __shared__ unsigned short s[128][66];
        const int bh    = blockIdx.x >> 1;
        const int chalf = blockIdx.x & 1;
        const size_t src_base = ((size_t)(bh >> 6) * CIN_ + chalf * 128) * (H_ * W_) + (bh & 63) * W_;
        #pragma unroll 4
        for (int k = 0; k < 32; ++k) {
            int i = k * 256 + tid;
            int c = i >> 6, wq = i & 63;
            s[c][wq] = f2bf(x[src_base + (size_t)c * (H_ * W_) + wq]);
        }
        __syncthreads();
        #pragma unroll 4
        for (int k = 0; k < 16; ++k) {
            int j  = k * 256 + tid;
            int c2 = (j & 63) * 2, wq = j >> 6;
            unsigned int lo = s[c2][wq], hi = s[c2 + 1][wq];
            *(unsigned int*)(xT + ((size_t)bh * 64 + wq) * 256 + chalf * 128 + c2) = lo | (hi << 16);
        }
    } else {
        // wb: 36 tiles [g][kk] of [o][pos*8+e], pos = j ^ (o&7), c = g*64 + j*8 + e
        const int base = (blockIdx.x - 512) * 1024 + tid * 4;
        #pragma unroll
        for (int u = 0; u < 4; ++u) {
            int idx = base + u;
            int e   = idx & 7;
            int pos = (idx >> 3) & 7;
            int o   = (idx >> 6) & 255;
            int t   = idx >> 14;
            int g   = t / 9, kk = t - g * 9;
            int j   = pos ^ (o & 7);
            int c   = g * 64 + j * 8 + e;
            wb[idx] = f2bf(w[(o * CIN_ + c) * KK_ + kk]);
        }
    }
}

// Main: block = (b, h row, deform group kq). Partial GEMM over K=576 quarter.
// kq0/kq1 -> bf16 pair packed in out words; kq2/kq3 -> ws. Last block per row reduces.
// NOTE: launch_bounds min-waves=4 (NOT 8): forcing 8 drove VGPR to 32 and spilled
// everything to scratch (R7: 314 MB fetch / 416 MB write of pure spill traffic).
// With natural VGPR (~50) the 40 KB LDS is the residency limiter: 4 blocks/CU.
__global__ __launch_bounds__(512, 4) void dcn_kernel(
    const unsigned short* __restrict__ xT, const float* __restrict__ y,
    const float* __restrict__ w_off, const unsigned short* __restrict__ wb,
    unsigned int* __restrict__ outu,        // d_out viewed as uint (bf16 pair)
    unsigned int* __restrict__ p23,         // ws partial pair for kq2/kq3
    int* __restrict__ cnt)
{
    __shared__ unsigned short s_W[COUT_ * 64];   // 32 KB
    __shared__ unsigned short s_S[TPX * 64];     //  8 KB  (reused as flag after loop)

    const int tid = threadIdx.x;
    const int bid = blockIdx.x;                  // 1024 blocks = 4/CU
    // XCD swizzle: bid&7 fixes (kq, b-low): wb quarter (288 KB) + x slab stay in L2
    const int kq  = bid & 3;
    const int bl  = (bid >> 2) & 1;
    const int loc = bid >> 3;                    // [0,128)
    const int h   = loc & 63;
    const int b   = (loc >> 6) * 2 + bl;
    const int row = b * 64 + h;

    // sampling mapping: thread -> (pixel sp, 8-ch chunk c8); 64*8 = 512 items
    const int sp = tid & 63;
    const int c8 = tid >> 6;

    const float yv0 = y[((b * 2 + 0) * H_ + h) * W_ + sp];
    const float yv1 = y[((b * 2 + 1) * H_ + h) * W_ + sp];

    // mfma mapping: 8 waves, wave = 64 outs (oh) x 32 px (pg)
    const int lane = tid & 63, wave = tid >> 6;
    const int pg  = wave & 1, oh = wave >> 1;
    const int l15 = lane & 15, kq4 = lane >> 4, sw = l15 & 7;

    f32x4 acc[8];
    #pragma unroll
    for (int i = 0; i < 8; ++i) acc[i] = (f32x4){0.f, 0.f, 0.f, 0.f};

    const size_t xbase = (size_t)b * (H_ * W_ * 256) + c8 * 8;

    for (int sl = 0; sl < NSL; ++sl) {
        const int s  = kq * NSL + sl;           // global step 0..35
        const int kk = sl;

        __syncthreads();   // all waves done reading s_W/s_S from prev step

        // ---- DMA W tile: 32 KB async global->LDS ----
        {
            const unsigned short* src = wb + (size_t)s * 16384;
            #pragma unroll
            for (int j = 0; j < 4; ++j) {
                const int off = (j * 512 + tid) * 8;
                __builtin_amdgcn_global_load_lds((gptr_t)(src + off),
                                                 (lptr_t)(s_W + off), 16, 0, 0);
            }
        }

        // ---- sample: 64 px x 64 ch ----
        {
            const float4 co = *(const float4*)(w_off + s * 4);
            const float dy = fmaf(yv0, co.x, yv1 * co.y);
            const float dx = fmaf(yv0, co.z, yv1 * co.w);
            const float yc = (float)(h + (kk / 3) - PAD_) + dy;
            const float xc = (float)(sp + (kk % 3) - PAD_) + dx;
            const float yf = floorf(yc), xf = floorf(xc);
            const float wy = yc - yf,    wx = xc - xf;
            const int   yi = (int)yf,    xi = (int)xf;
            float w00 = (1.f - wy) * (1.f - wx);
            float w01 = (1.f - wy) * wx;
            float w10 = wy * (1.f - wx);
            float w11 = wy * wx;
            const bool y0ok = (yi >= 0) & (yi < H_);
            const bool y1ok = (yi >= -1) & (yi < H_ - 1);
            const bool x0ok = (xi >= 0) & (xi < W_);
            const bool x1ok = (xi >= -1) & (xi < W_ - 1);
            w00 = (y0ok & x0ok) ? w00 : 0.f;
            w01 = (y0ok & x1ok) ? w01 : 0.f;
            w10 = (y1ok & x0ok) ? w10 : 0.f;
            w11 = (y1ok & x1ok) ? w11 : 0.f;
            const int y0c = min(max(yi, 0), H_ - 1);
            const int y1c = min(max(yi + 1, 0), H_ - 1);
            const int x0c = min(max(xi, 0), W_ - 1);
            const int x1c = min(max(xi + 1, 0), W_ - 1);
            const unsigned short* xb = xT + xbase + kq * 64;
            const uint4 A  = *(const uint4*)(xb + ((size_t)y0c * W_ + x0c) * 256);
            const uint4 Bv = *(const uint4*)(xb + ((size_t)y0c * W_ + x1c) * 256);
            const uint4 C  = *(const uint4*)(xb + ((size_t)y1c * W_ + x0c) * 256);
            const uint4 D  = *(const uint4*)(xb + ((size_t)y1c * W_ + x1c) * 256);
            const unsigned int av[4] = {A.x, A.y, A.z, A.w};
            const unsigned int bv[4] = {Bv.x, Bv.y, Bv.z, Bv.w};
            const unsigned int cv[4] = {C.x, C.y, C.z, C.w};
            const unsigned int dv[4] = {D.x, D.y, D.z, D.w};
            unsigned int res[4];
            #pragma unroll
            for (int q = 0; q < 4; ++q) {
                float rl = w00 * f_lo(av[q]);
                rl = fmaf(w01, f_lo(bv[q]), rl);
                rl = fmaf(w10, f_lo(cv[q]), rl);
                rl = fmaf(w11, f_lo(dv[q]), rl);
                float rh = w00 * f_hi(av[q]);
                rh = fmaf(w01, f_hi(bv[q]), rh);
                rh = fmaf(w10, f_hi(cv[q]), rh);
                rh = fmaf(w11, f_hi(dv[q]), rh);
                res[q] = __builtin_amdgcn_perm(__float_as_uint(rh),
                                               __float_as_uint(rl), 0x07060302u);
            }
            *(uint4*)(s_S + sp * 64 + ((c8 ^ (sp & 7)) * 8)) =
                make_uint4(res[0], res[1], res[2], res[3]);
        }

        __syncthreads();   // drains DMA + LDS stores

        // ---- MFMA: wave = [oh*64,+64) outs x [pg*32,+32) px, K=64 ----
        bf16x8 bf[2][2], af[2][4];
        #pragma unroll
        for (int kh = 0; kh < 2; ++kh) {
            const int pos = ((kh * 4 + kq4) ^ sw) * 8;
            #pragma unroll
            for (int nt = 0; nt < 2; ++nt)
                bf[kh][nt] = *(const bf16x8*)(s_S + (pg * 32 + nt * 16 + l15) * 64 + pos);
            #pragma unroll
            for (int mt = 0; mt < 4; ++mt)
                af[kh][mt] = *(const bf16x8*)(s_W + (oh * 64 + mt * 16 + l15) * 64 + pos);
        }
        #pragma unroll
        for (int kh = 0; kh < 2; ++kh)
            #pragma unroll
            for (int nt = 0; nt < 2; ++nt)
                #pragma unroll
                for (int mt = 0; mt < 4; ++mt)
                    acc[nt * 4 + mt] = __builtin_amdgcn_mfma_f32_16x16x32_bf16(
                        af[kh][mt], bf[kh][nt], acc[nt * 4 + mt], 0, 0, 0);
    }

    // ---- store bf16 partial into packed pair word (lo: kq even, hi: kq odd) ----
    {
        unsigned short* pdst =
            (unsigned short*)((kq < 2) ? outu : p23) + (kq & 1);
        #pragma unroll
        for (int nt = 0; nt < 2; ++nt) {
            const int px = pg * 32 + nt * 16 + l15;
            #pragma unroll
            for (int mt = 0; mt < 4; ++mt) {
                const int obase = oh * 64 + mt * 16 + kq4 * 4;
                #pragma unroll
                for (int r = 0; r < 4; ++r) {
                    const size_t gi = (((size_t)b * COUT_ + obase + r) * H_ + h) * W_ + px;
                    pdst[gi * 2] = f2bf(acc[nt * 4 + mt][r]);
                }
            }
        }
    }

    // ---- last-block-per-row reduction: out = relu(p0+p1+p2+p3) ----
    __threadfence();
    __syncthreads();
    int* s_flag = (int*)s_S;           // s_S dead after MFMA loop
    if (tid == 0) s_flag[0] = (atomicAdd(&cnt[row], 1) == 3);
    __syncthreads();
    if (s_flag[0]) {
        __threadfence();               // acquire: see other blocks' partials
        const size_t base = (size_t)b * (COUT_ * H_ * W_) + (size_t)h * W_;
        float* outf = (float*)outu;
        #pragma unroll
        for (int j = 0; j < 8; ++j) {
            const int e = j * 2048 + tid * 4;     // o*64 + w within the row
            const int o = e >> 6, wq = e & 63;
            const size_t gi = base + (size_t)o * (H_ * W_) + wq;
            const uint4 a = *(const uint4*)(outu + gi);
            const uint4 c = *(const uint4*)(p23 + gi);
            float4 r;
            r.x = fmaxf(f_lo(a.x) + f_hi(a.x) + f_lo(c.x) + f_hi(c.x), 0.f);
            r.y = fmaxf(f_lo(a.y) + f_hi(a.y) + f_lo(c.y) + f_hi(c.y), 0.f);
            r.z = fmaxf(f_lo(a.z) + f_hi(a.z) + f_lo(c.z) + f_hi(c.z), 0.f);
            r.w = fmaxf(f_lo(a.w) + f_hi(a.w) + f_lo(c.w) + f_hi(c.w), 0.f);
            *(float4*)(outf + gi) = r;
        }
    }
}

extern "C" void kernel_launch(void* const* d_in, const int* in_sizes, int n_in,
                              void* d_out, int out_size, void* d_ws, size_t ws_size,
                              hipStream_t stream) {
    const float* x     = (const float*)d_in[0];
    const float* y     = (const float*)d_in[1];
    const float* w_off = (const float*)d_in[2];
    const float* w_def = (const float*)d_in[3];

    unsigned short* xT  = (unsigned short*)((char*)d_ws + WS_XT);
    unsigned short* wb  = (unsigned short*)((char*)d_ws + WS_WB);
    unsigned int*   p23 = (unsigned int*)((char*)d_ws + WS_P23);
    int*            cnt = (int*)((char*)d_ws + WS_CNT);

    hipMemsetAsync(cnt, 0, 256 * sizeof(int), stream);
    prep_kernel<<<1088, 256, 0, stream>>>(x, w_def, xT, wb);
    dcn_kernel<<<1024, 512, 0, stream>>>(xT, y, w_off, wb,
                                         (unsigned int*)d_out, p23, cnt);
}

// Round 9
// 140.320 us; speedup vs baseline: 4.7366x; 4.3962x over previous
//
#include <hip/hip_runtime.h>
#include <cstddef>

#define B_    4
#define CIN_  256
#define COUT_ 256
#define H_    64
#define W_    64
#define KK_   9
#define G_    4
#define PAD_  1
#define TPX   64          // pixels per block = one full W row
#define NSL   9           // steps per block: 1 group * 9 taps, K=64 each

// ws layout (bytes)
#define WS_XT   0u          // 8 MB bf16 NHWC x
#define WS_WB   8388608u    // 1.18 MB bf16 weights
#define WS_P23  9568256u    // 16.8 MB: uint per out elem = [p2|p3] bf16 pair

typedef short bf16x8 __attribute__((ext_vector_type(8)));
typedef float f32x4  __attribute__((ext_vector_type(4)));
typedef __attribute__((address_space(1))) const unsigned int* gptr_t;
typedef __attribute__((address_space(3))) unsigned int*       lptr_t;

__device__ __forceinline__ unsigned short f2bf(float v) {
    unsigned int u = __float_as_uint(v);
    u += 0x7fffu + ((u >> 16) & 1u);
    return (unsigned short)(u >> 16);
}
__device__ __forceinline__ float f_lo(unsigned int u) { return __uint_as_float(u << 16); }
__device__ __forceinline__ float f_hi(unsigned int u) { return __uint_as_float(u & 0xffff0000u); }

// Fused prep: blocks [0,512) transpose x -> NHWC bf16; blocks [512,1088) build wb.
__global__ __launch_bounds__(256) void prep_kernel(const float* __restrict__ x,
                                                   const float* __restrict__ w,
                                                   unsigned short* __restrict__ xT,
                                                   unsigned short* __restrict__ wb) {
    const int tid = threadIdx.x;
    if (blockIdx.x < 512) {
        __shared__ unsigned short s[128][66];
        const int bh    = blockIdx.x >> 1;
        const int chalf = blockIdx.x & 1;
        const size_t src_base = ((size_t)(bh >> 6) * CIN_ + chalf * 128) * (H_ * W_) + (bh & 63) * W_;
        #pragma unroll 4
        for (int k = 0; k < 32; ++k) {
            int i = k * 256 + tid;
            int c = i >> 6, wq = i & 63;
            s[c][wq] = f2bf(x[src_base + (size_t)c * (H_ * W_) + wq]);
        }
        __syncthreads();
        #pragma unroll 4
        for (int k = 0; k < 16; ++k) {
            int j  = k * 256 + tid;
            int c2 = (j & 63) * 2, wq = j >> 6;
            unsigned int lo = s[c2][wq], hi = s[c2 + 1][wq];
            *(unsigned int*)(xT + ((size_t)bh * 64 + wq) * 256 + chalf * 128 + c2) = lo | (hi << 16);
        }
    } else {
        // wb: 36 tiles [g][kk] of [o][pos*8+e], pos = j ^ (o&7), c = g*64 + j*8 + e
        const int base = (blockIdx.x - 512) * 1024 + tid * 4;
        #pragma unroll
        for (int u = 0; u < 4; ++u) {
            int idx = base + u;
            int e   = idx & 7;
            int pos = (idx >> 3) & 7;
            int o   = (idx >> 6) & 255;
            int t   = idx >> 14;
            int g   = t / 9, kk = t - g * 9;
            int j   = pos ^ (o & 7);
            int c   = g * 64 + j * 8 + e;
            wb[idx] = f2bf(w[(o * CIN_ + c) * KK_ + kk]);
        }
    }
}

// Main: block = (b, h row, deform group kq). Partial GEMM over a K=576 quarter.
// Partials are bf16 packed pairwise: kq0/kq1 -> lo/hi ushort of each outu word,
// kq2/kq3 -> lo/hi of p23. Plain stores (byte-enable merging across blocks is
// safe; cross-XCD visibility comes from the kernel boundary before red_kernel).
// NO fences/atomics in here: R7/R8 showed per-block __threadfence (full L2
// writeback on non-coherent XCD L2s) serializes the GPU -> 10x regression.
// launch_bounds min-waves=4 (NOT 8: that forced VGPR=32 and spilled, R7).
__global__ __launch_bounds__(512, 4) void dcn_kernel(
    const unsigned short* __restrict__ xT, const float* __restrict__ y,
    const float* __restrict__ w_off, const unsigned short* __restrict__ wb,
    unsigned int* __restrict__ outu,        // d_out viewed as uint (bf16 pair)
    unsigned int* __restrict__ p23)         // ws partial pair for kq2/kq3
{
    __shared__ unsigned short s_W[COUT_ * 64];   // 32 KB
    __shared__ unsigned short s_S[TPX * 64];     //  8 KB

    const int tid = threadIdx.x;
    const int bid = blockIdx.x;                  // 1024 blocks = 4/CU
    // XCD swizzle: bid&7 fixes (kq, b-low): wb quarter (288 KB) + x slab stay in L2
    const int kq  = bid & 3;
    const int bl  = (bid >> 2) & 1;
    const int loc = bid >> 3;                    // [0,128)
    const int h   = loc & 63;
    const int b   = (loc >> 6) * 2 + bl;

    // sampling mapping: thread -> (pixel sp, 8-ch chunk c8); 64*8 = 512 items
    const int sp = tid & 63;
    const int c8 = tid >> 6;

    const float yv0 = y[((b * 2 + 0) * H_ + h) * W_ + sp];
    const float yv1 = y[((b * 2 + 1) * H_ + h) * W_ + sp];

    // mfma mapping: 8 waves, wave = 64 outs (oh) x 32 px (pg)
    const int lane = tid & 63, wave = tid >> 6;
    const int pg  = wave & 1, oh = wave >> 1;
    const int l15 = lane & 15, kq4 = lane >> 4, sw = l15 & 7;

    f32x4 acc[8];
    #pragma unroll
    for (int i = 0; i < 8; ++i) acc[i] = (f32x4){0.f, 0.f, 0.f, 0.f};

    const size_t xbase = (size_t)b * (H_ * W_ * 256) + c8 * 8;

    for (int sl = 0; sl < NSL; ++sl) {
        const int s  = kq * NSL + sl;           // global step 0..35
        const int kk = sl;

        __syncthreads();   // all waves done reading s_W/s_S from prev step

        // ---- DMA W tile: 32 KB async global->LDS ----
        {
            const unsigned short* src = wb + (size_t)s * 16384;
            #pragma unroll
            for (int j = 0; j < 4; ++j) {
                const int off = (j * 512 + tid) * 8;
                __builtin_amdgcn_global_load_lds((gptr_t)(src + off),
                                                 (lptr_t)(s_W + off), 16, 0, 0);
            }
        }

        // ---- sample: 64 px x 64 ch ----
        {
            const float4 co = *(const float4*)(w_off + s * 4);
            const float dy = fmaf(yv0, co.x, yv1 * co.y);
            const float dx = fmaf(yv0, co.z, yv1 * co.w);
            const float yc = (float)(h + (kk / 3) - PAD_) + dy;
            const float xc = (float)(sp + (kk % 3) - PAD_) + dx;
            const float yf = floorf(yc), xf = floorf(xc);
            const float wy = yc - yf,    wx = xc - xf;
            const int   yi = (int)yf,    xi = (int)xf;
            float w00 = (1.f - wy) * (1.f - wx);
            float w01 = (1.f - wy) * wx;
            float w10 = wy * (1.f - wx);
            float w11 = wy * wx;
            const bool y0ok = (yi >= 0) & (yi < H_);
            const bool y1ok = (yi >= -1) & (yi < H_ - 1);
            const bool x0ok = (xi >= 0) & (xi < W_);
            const bool x1ok = (xi >= -1) & (xi < W_ - 1);
            w00 = (y0ok & x0ok) ? w00 : 0.f;
            w01 = (y0ok & x1ok) ? w01 : 0.f;
            w10 = (y1ok & x0ok) ? w10 : 0.f;
            w11 = (y1ok & x1ok) ? w11 : 0.f;
            const int y0c = min(max(yi, 0), H_ - 1);
            const int y1c = min(max(yi + 1, 0), H_ - 1);
            const int x0c = min(max(xi, 0), W_ - 1);
            const int x1c = min(max(xi + 1, 0), W_ - 1);
            const unsigned short* xb = xT + xbase + kq * 64;
            const uint4 A  = *(const uint4*)(xb + ((size_t)y0c * W_ + x0c) * 256);
            const uint4 Bv = *(const uint4*)(xb + ((size_t)y0c * W_ + x1c) * 256);
            const uint4 C  = *(const uint4*)(xb + ((size_t)y1c * W_ + x0c) * 256);
            const uint4 D  = *(const uint4*)(xb + ((size_t)y1c * W_ + x1c) * 256);
            const unsigned int av[4] = {A.x, A.y, A.z, A.w};
            const unsigned int bv[4] = {Bv.x, Bv.y, Bv.z, Bv.w};
            const unsigned int cv[4] = {C.x, C.y, C.z, C.w};
            const unsigned int dv[4] = {D.x, D.y, D.z, D.w};
            unsigned int res[4];
            #pragma unroll
            for (int q = 0; q < 4; ++q) {
                float rl = w00 * f_lo(av[q]);
                rl = fmaf(w01, f_lo(bv[q]), rl);
                rl = fmaf(w10, f_lo(cv[q]), rl);
                rl = fmaf(w11, f_lo(dv[q]), rl);
                float rh = w00 * f_hi(av[q]);
                rh = fmaf(w01, f_hi(bv[q]), rh);
                rh = fmaf(w10, f_hi(cv[q]), rh);
                rh = fmaf(w11, f_hi(dv[q]), rh);
                res[q] = __builtin_amdgcn_perm(__float_as_uint(rh),
                                               __float_as_uint(rl), 0x07060302u);
            }
            *(uint4*)(s_S + sp * 64 + ((c8 ^ (sp & 7)) * 8)) =
                make_uint4(res[0], res[1], res[2], res[3]);
        }

        __syncthreads();   // drains DMA + LDS stores

        // ---- MFMA: wave = [oh*64,+64) outs x [pg*32,+32) px, K=64 ----
        bf16x8 bf[2][2], af[2][4];
        #pragma unroll
        for (int kh = 0; kh < 2; ++kh) {
            const int pos = ((kh * 4 + kq4) ^ sw) * 8;
            #pragma unroll
            for (int nt = 0; nt < 2; ++nt)
                bf[kh][nt] = *(const bf16x8*)(s_S + (pg * 32 + nt * 16 + l15) * 64 + pos);
            #pragma unroll
            for (int mt = 0; mt < 4; ++mt)
                af[kh][mt] = *(const bf16x8*)(s_W + (oh * 64 + mt * 16 + l15) * 64 + pos);
        }
        #pragma unroll
        for (int kh = 0; kh < 2; ++kh)
            #pragma unroll
            for (int nt = 0; nt < 2; ++nt)
                #pragma unroll
                for (int mt = 0; mt < 4; ++mt)
                    acc[nt * 4 + mt] = __builtin_amdgcn_mfma_f32_16x16x32_bf16(
                        af[kh][mt], bf[kh][nt], acc[nt * 4 + mt], 0, 0, 0);
    }

    // ---- store bf16 partial into packed pair word (lo: kq even, hi: kq odd) ----
    unsigned short* pdst = (unsigned short*)((kq < 2) ? outu : p23) + (kq & 1);
    #pragma unroll
    for (int nt = 0; nt < 2; ++nt) {
        const int px = pg * 32 + nt * 16 + l15;
        #pragma unroll
        for (int mt = 0; mt < 4; ++mt) {
            const int obase = oh * 64 + mt * 16 + kq4 * 4;
            #pragma unroll
            for (int r = 0; r < 4; ++r) {
                const size_t gi = (((size_t)b * COUT_ + obase + r) * H_ + h) * W_ + px;
                pdst[gi * 2] = f2bf(acc[nt * 4 + mt][r]);
            }
        }
    }
}

// out = relu(lo(out)+hi(out)+lo(p23)+hi(p23)) elementwise; in-place over d_out.
__global__ __launch_bounds__(256) void red_kernel(const unsigned int* __restrict__ p23,
                                                  unsigned int* __restrict__ outu) {
    const size_t i = ((size_t)blockIdx.x * 256 + threadIdx.x) * 4;
    const uint4 a = *(const uint4*)(outu + i);
    const uint4 c = *(const uint4*)(p23 + i);
    float4 r;
    r.x = fmaxf(f_lo(a.x) + f_hi(a.x) + f_lo(c.x) + f_hi(c.x), 0.f);
    r.y = fmaxf(f_lo(a.y) + f_hi(a.y) + f_lo(c.y) + f_hi(c.y), 0.f);
    r.z = fmaxf(f_lo(a.z) + f_hi(a.z) + f_lo(c.z) + f_hi(c.z), 0.f);
    r.w = fmaxf(f_lo(a.w) + f_hi(a.w) + f_lo(c.w) + f_hi(c.w), 0.f);
    *(float4*)((float*)outu + i) = r;
}

extern "C" void kernel_launch(void* const* d_in, const int* in_sizes, int n_in,
                              void* d_out, int out_size, void* d_ws, size_t ws_size,
                              hipStream_t stream) {
    const float* x     = (const float*)d_in[0];
    const float* y     = (const float*)d_in[1];
    const float* w_off = (const float*)d_in[2];
    const float* w_def = (const float*)d_in[3];

    unsigned short* xT  = (unsigned short*)((char*)d_ws + WS_XT);
    unsigned short* wb  = (unsigned short*)((char*)d_ws + WS_WB);
    unsigned int*   p23 = (unsigned int*)((char*)d_ws + WS_P23);

    prep_kernel<<<1088, 256, 0, stream>>>(x, w_def, xT, wb);
    dcn_kernel<<<1024, 512, 0, stream>>>(xT, y, w_off, wb,
                                         (unsigned int*)d_out, p23);
    red_kernel<<<(B_ * COUT_ * H_ * W_) / 4 / 256, 256, 0, stream>>>(
        p23, (unsigned int*)d_out);
}

// Round 11
// 138.841 us; speedup vs baseline: 4.7871x; 1.0107x over previous
//
#include <hip/hip_runtime.h>
#include <cstddef>

#define B_    4
#define CIN_  256
#define COUT_ 256
#define H_    64
#define W_    64
#define KK_   9
#define G_    4
#define PAD_  1
#define TPX   64          // pixels per block = one full W row
#define NSL   9           // steps per block: 1 group * 9 taps, K=64 each

// ws layout (bytes)
#define WS_XT   0u          // 8 MB bf16 NHWC x
#define WS_WB   8388608u    // 1.18 MB bf16 weights
#define WS_P23  9568256u    // 16.8 MB: uint per out elem = [p2|p3] bf16 pair

typedef short bf16x8 __attribute__((ext_vector_type(8)));
typedef float f32x4  __attribute__((ext_vector_type(4)));
typedef __attribute__((address_space(1))) const unsigned int* gptr_t;
typedef __attribute__((address_space(3))) unsigned int*       lptr_t;

__device__ __forceinline__ unsigned short f2bf(float v) {
    unsigned int u = __float_as_uint(v);
    u += 0x7fffu + ((u >> 16) & 1u);
    return (unsigned short)(u >> 16);
}
__device__ __forceinline__ float f_lo(unsigned int u) { return __uint_as_float(u << 16); }
__device__ __forceinline__ float f_hi(unsigned int u) { return __uint_as_float(u & 0xffff0000u); }

// Fused prep: blocks [0,512) transpose x -> NHWC bf16; blocks [512,1088) build wb.
__global__ __launch_bounds__(256) void prep_kernel(const float* __restrict__ x,
                                                   const float* __restrict__ w,
                                                   unsigned short* __restrict__ xT,
                                                   unsigned short* __restrict__ wb) {
    const int tid = threadIdx.x;
    if (blockIdx.x < 512) {
        __shared__ unsigned short s[128][66];
        const int bh    = blockIdx.x >> 1;
        const int chalf = blockIdx.x & 1;
        const size_t src_base = ((size_t)(bh >> 6) * CIN_ + chalf * 128) * (H_ * W_) + (bh & 63) * W_;
        #pragma unroll 4
        for (int k = 0; k < 32; ++k) {
            int i = k * 256 + tid;
            int c = i >> 6, wq = i & 63;
            s[c][wq] = f2bf(x[src_base + (size_t)c * (H_ * W_) + wq]);
        }
        __syncthreads();
        #pragma unroll 4
        for (int k = 0; k < 16; ++k) {
            int j  = k * 256 + tid;
            int c2 = (j & 63) * 2, wq = j >> 6;
            unsigned int lo = s[c2][wq], hi = s[c2 + 1][wq];
            *(unsigned int*)(xT + ((size_t)bh * 64 + wq) * 256 + chalf * 128 + c2) = lo | (hi << 16);
        }
    } else {
        // wb: 36 tiles [g][kk] of [o][pos*8+e], pos = j ^ (o&7), c = g*64 + j*8 + e
        const int base = (blockIdx.x - 512) * 1024 + tid * 4;
        #pragma unroll
        for (int u = 0; u < 4; ++u) {
            int idx = base + u;
            int e   = idx & 7;
            int pos = (idx >> 3) & 7;
            int o   = (idx >> 6) & 255;
            int t   = idx >> 14;
            int g   = t / 9, kk = t - g * 9;
            int j   = pos ^ (o & 7);
            int c   = g * 64 + j * 8 + e;
            wb[idx] = f2bf(w[(o * CIN_ + c) * KK_ + kk]);
        }
    }
}

struct SampRegs {
    uint4 A, Bv, C, D;
    float w00, w01, w10, w11;
};

// Main: block = (b, h row, deform group kq); partial GEMM over a K=576 quarter.
// Pipeline = R4's PROVEN double-buffered shape (one barrier per step): at step
// sl we issue W-DMA + gather loads for sl+1 into buf^1, run MFMA on buf, then
// combine+store samples into buf^1, barrier. Every load has a full MFMA phase
// before its drain. (R10's single-buffer register-staged variant miscomputed;
// reverted to this structure which passed at R4.)
// NO fences/atomics (R8: per-block threadfence = 10x regression).
// launch_bounds min-waves=4 (R7: forcing 8 -> VGPR 32 -> total spill).
__global__ __launch_bounds__(512, 4) void dcn_kernel(
    const unsigned short* __restrict__ xT, const float* __restrict__ y,
    const float* __restrict__ w_off, const unsigned short* __restrict__ wb,
    unsigned int* __restrict__ outu,        // d_out viewed as uint (bf16 pair)
    unsigned int* __restrict__ p23)         // ws partial pair for kq2/kq3
{
    __shared__ unsigned short s_W[2][COUT_ * 64];   // 2 x 32 KB (dbuf)
    __shared__ unsigned short s_S[2][TPX * 64];     // 2 x  8 KB (dbuf)

    const int tid = threadIdx.x;
    const int bid = blockIdx.x;                  // 1024 blocks
    // XCD swizzle: bid&7 fixes (kq, b-low): wb quarter + x slab stay in L2
    const int kq  = bid & 3;
    const int bl  = (bid >> 2) & 1;
    const int loc = bid >> 3;                    // [0,128)
    const int h   = loc & 63;
    const int b   = (loc >> 6) * 2 + bl;

    // sampling mapping: thread -> (pixel sp, 8-ch chunk c8); 64*8 = 512 items
    const int sp = tid & 63;
    const int c8 = tid >> 6;

    const float yv0 = y[((b * 2 + 0) * H_ + h) * W_ + sp];
    const float yv1 = y[((b * 2 + 1) * H_ + h) * W_ + sp];

    // mfma mapping: 8 waves, wave = 64 outs (oh) x 32 px (pg)
    const int lane = tid & 63, wave = tid >> 6;
    const int pg  = wave & 1, oh = wave >> 1;
    const int l15 = lane & 15, kq4 = lane >> 4, sw = l15 & 7;

    f32x4 acc[8];
    #pragma unroll
    for (int i = 0; i < 8; ++i) acc[i] = (f32x4){0.f, 0.f, 0.f, 0.f};

    const size_t xbase = (size_t)b * (H_ * W_ * 256) + c8 * 8;

    auto dma_w = [&](int s, int buf) {
        const unsigned short* src = wb + (size_t)s * 16384;
        unsigned short* dst = &s_W[buf][0];
        #pragma unroll
        for (int j = 0; j < 4; ++j) {
            const int off = (j * 512 + tid) * 8;       // 16 B per thread per pass
            __builtin_amdgcn_global_load_lds((gptr_t)(src + off),
                                             (lptr_t)(dst + off), 16, 0, 0);
        }
    };

    // phase 1: issue corner loads + compute weights (loads stay in flight)
    auto sample_load = [&](int sl) -> SampRegs {
        SampRegs r;
        const int s  = kq * NSL + sl;                 // global step for w_off
        const int kk = sl;                            // tap within the group
        const float4 co = *(const float4*)(w_off + s * 4);   // uniform scalar load
        const float dy = fmaf(yv0, co.x, yv1 * co.y);
        const float dx = fmaf(yv0, co.z, yv1 * co.w);
        const float yc = (float)(h + (kk / 3) - PAD_) + dy;
        const float xc = (float)(sp + (kk % 3) - PAD_) + dx;
        const float yf = floorf(yc), xf = floorf(xc);
        const float wy = yc - yf,    wx = xc - xf;
        const int   yi = (int)yf,    xi = (int)xf;
        float w00 = (1.f - wy) * (1.f - wx);
        float w01 = (1.f - wy) * wx;
        float w10 = wy * (1.f - wx);
        float w11 = wy * wx;
        const bool y0ok = (yi >= 0) & (yi < H_);
        const bool y1ok = (yi >= -1) & (yi < H_ - 1);
        const bool x0ok = (xi >= 0) & (xi < W_);
        const bool x1ok = (xi >= -1) & (xi < W_ - 1);
        r.w00 = (y0ok & x0ok) ? w00 : 0.f;
        r.w01 = (y0ok & x1ok) ? w01 : 0.f;
        r.w10 = (y1ok & x0ok) ? w10 : 0.f;
        r.w11 = (y1ok & x1ok) ? w11 : 0.f;
        const int y0c = min(max(yi, 0), H_ - 1);
        const int y1c = min(max(yi + 1, 0), H_ - 1);
        const int x0c = min(max(xi, 0), W_ - 1);
        const int x1c = min(max(xi + 1, 0), W_ - 1);
        const unsigned short* xb = xT + xbase + kq * 64;
        r.A  = *(const uint4*)(xb + ((size_t)y0c * W_ + x0c) * 256);
        r.Bv = *(const uint4*)(xb + ((size_t)y0c * W_ + x1c) * 256);
        r.C  = *(const uint4*)(xb + ((size_t)y1c * W_ + x0c) * 256);
        r.D  = *(const uint4*)(xb + ((size_t)y1c * W_ + x1c) * 256);
        return r;
    };

    // phase 2: bilinear combine + pack + LDS store
    auto sample_store = [&](const SampRegs& r, int buf) {
        const unsigned int av[4] = {r.A.x, r.A.y, r.A.z, r.A.w};
        const unsigned int bv[4] = {r.Bv.x, r.Bv.y, r.Bv.z, r.Bv.w};
        const unsigned int cv[4] = {r.C.x, r.C.y, r.C.z, r.C.w};
        const unsigned int dv[4] = {r.D.x, r.D.y, r.D.z, r.D.w};
        unsigned int res[4];
        #pragma unroll
        for (int q = 0; q < 4; ++q) {
            float rl = r.w00 * f_lo(av[q]);
            rl = fmaf(r.w01, f_lo(bv[q]), rl);
            rl = fmaf(r.w10, f_lo(cv[q]), rl);
            rl = fmaf(r.w11, f_lo(dv[q]), rl);
            float rh = r.w00 * f_hi(av[q]);
            rh = fmaf(r.w01, f_hi(bv[q]), rh);
            rh = fmaf(r.w10, f_hi(cv[q]), rh);
            rh = fmaf(r.w11, f_hi(dv[q]), rh);
            res[q] = __builtin_amdgcn_perm(__float_as_uint(rh),
                                           __float_as_uint(rl), 0x07060302u);
        }
        *(uint4*)(&s_S[buf][0] + sp * 64 + ((c8 ^ (sp & 7)) * 8)) =
            make_uint4(res[0], res[1], res[2], res[3]);
    };

    // ---------------- software-pipelined main loop (R4 shape) ----------------
    dma_w(kq * NSL, 0);
    {
        SampRegs r0 = sample_load(0);
        sample_store(r0, 0);
    }
    __syncthreads();

    for (int sl = 0; sl < NSL; ++sl) {
        const int cur = sl & 1;
        SampRegs rn;
        if (sl < NSL - 1) {
            dma_w(kq * NSL + sl + 1, cur ^ 1);
            rn = sample_load(sl + 1);     // corner loads in flight across MFMA
        }

        const unsigned short* Wb = &s_W[cur][0];
        const unsigned short* Sb = &s_S[cur][0];
        #pragma unroll
        for (int kh = 0; kh < 2; ++kh) {
            const int pos = ((kh * 4 + kq4) ^ sw) * 8;
            bf16x8 bf[2], af[4];
            #pragma unroll
            for (int nt = 0; nt < 2; ++nt)
                bf[nt] = *(const bf16x8*)(Sb + (pg * 32 + nt * 16 + l15) * 64 + pos);
            #pragma unroll
            for (int mt = 0; mt < 4; ++mt)
                af[mt] = *(const bf16x8*)(Wb + (oh * 64 + mt * 16 + l15) * 64 + pos);
            #pragma unroll
            for (int nt = 0; nt < 2; ++nt)
                #pragma unroll
                for (int mt = 0; mt < 4; ++mt)
                    acc[nt * 4 + mt] = __builtin_amdgcn_mfma_f32_16x16x32_bf16(
                        af[mt], bf[nt], acc[nt * 4 + mt], 0, 0, 0);
        }

        if (sl < NSL - 1) sample_store(rn, cur ^ 1);
        __syncthreads();   // fences next buffer's DMA + LDS stores; frees cur
    }

    // ---- store bf16 partial into packed pair word (lo: kq even, hi: kq odd) ----
    unsigned short* pdst = (unsigned short*)((kq < 2) ? outu : p23) + (kq & 1);
    #pragma unroll
    for (int nt = 0; nt < 2; ++nt) {
        const int px = pg * 32 + nt * 16 + l15;
        #pragma unroll
        for (int mt = 0; mt < 4; ++mt) {
            const int obase = oh * 64 + mt * 16 + kq4 * 4;
            #pragma unroll
            for (int r = 0; r < 4; ++r) {
                const size_t gi = (((size_t)b * COUT_ + obase + r) * H_ + h) * W_ + px;
                pdst[gi * 2] = f2bf(acc[nt * 4 + mt][r]);
            }
        }
    }
}

// out = relu(lo(out)+hi(out)+lo(p23)+hi(p23)) elementwise; in-place over d_out.
__global__ __launch_bounds__(256) void red_kernel(const unsigned int* __restrict__ p23,
                                                  unsigned int* __restrict__ outu) {
    const size_t i = ((size_t)blockIdx.x * 256 + threadIdx.x) * 4;
    const uint4 a = *(const uint4*)(outu + i);
    const uint4 c = *(const uint4*)(p23 + i);
    float4 r;
    r.x = fmaxf(f_lo(a.x) + f_hi(a.x) + f_lo(c.x) + f_hi(c.x), 0.f);
    r.y = fmaxf(f_lo(a.y) + f_hi(a.y) + f_lo(c.y) + f_hi(c.y), 0.f);
    r.z = fmaxf(f_lo(a.z) + f_hi(a.z) + f_lo(c.z) + f_hi(c.z), 0.f);
    r.w = fmaxf(f_lo(a.w) + f_hi(a.w) + f_lo(c.w) + f_hi(c.w), 0.f);
    *(float4*)((float*)outu + i) = r;
}

extern "C" void kernel_launch(void* const* d_in, const int* in_sizes, int n_in,
                              void* d_out, int out_size, void* d_ws, size_t ws_size,
                              hipStream_t stream) {
    const float* x     = (const float*)d_in[0];
    const float* y     = (const float*)d_in[1];
    const float* w_off = (const float*)d_in[2];
    const float* w_def = (const float*)d_in[3];

    unsigned short* xT  = (unsigned short*)((char*)d_ws + WS_XT);
    unsigned short* wb  = (unsigned short*)((char*)d_ws + WS_WB);
    unsigned int*   p23 = (unsigned int*)((char*)d_ws + WS_P23);

    prep_kernel<<<1088, 256, 0, stream>>>(x, w_def, xT, wb);
    dcn_kernel<<<1024, 512, 0, stream>>>(xT, y, w_off, wb,
                                         (unsigned int*)d_out, p23);
    red_kernel<<<(B_ * COUT_ * H_ * W_) / 4 / 256, 256, 0, stream>>>(
        p23, (unsigned int*)d_out);
}